// Round 12
// baseline (213.840 us; speedup 1.0000x reference)
//
#include <hip/hip_runtime.h>
#include <hip/hip_bf16.h>
#include <math.h>

#define N_NODES 100000
#define N_EDGES 1600000
#define F_IN 165
#define HID 64
#define SLOPE 0.2f

#define NBUCK 196          // ceil(N_NODES / 512) buckets of 512 nodes
#define BSHIFT 9           // 512 nodes per bucket
#define BMASK 511
#define NBLK 256           // partition blocks
#define CHUNK 6250         // edges per partition block (256*6250 == 1.6M)
#define MSCAN (NBUCK * NBLK)   // 50176 scan elements

typedef short short8 __attribute__((ext_vector_type(8)));
typedef float f32x4 __attribute__((ext_vector_type(4)));
typedef float f32x2 __attribute__((ext_vector_type(2)));

__device__ __forceinline__ float lrelu(float x) { return x > 0.f ? x : SLOPE * x; }

__device__ __forceinline__ unsigned short f2bf(float f) {
    unsigned u = __float_as_uint(f);
    u += 0x7FFFu + ((u >> 16) & 1u);
    return (unsigned short)(u >> 16);
}
__device__ __forceinline__ float bflo(unsigned u) { return __uint_as_float(u << 16); }
__device__ __forceinline__ float bfhi(unsigned u) { return __uint_as_float(u & 0xFFFF0000u); }
__device__ __forceinline__ unsigned char f2fp8(float f) {
    return (unsigned char)(__builtin_amdgcn_cvt_pk_fp8_f32(f, f, 0, false) & 0xFF);
}

// ---- pass A1: bucket histogram + edge cast + (fused) W1 swizzle ----
__global__ __launch_bounds__(256) void k_hist(const int* __restrict__ ei,
                                              int* __restrict__ hist,
                                              float* __restrict__ out_edges,
                                              const float* __restrict__ W1,
                                              unsigned short* __restrict__ Wsw) {
    int blk = blockIdx.x, t = threadIdx.x;
    int idx = blk * 256 + t;
    if (idx < 12288) {
        int j = idx & 7;
        int r = idx >> 3;
        int n = r & 15; r >>= 4;
        int tt = r & 3; r >>= 2;
        int q = r & 3;  int c = r >> 2;
        int k = c * 32 + q * 8 + j;
        int col = tt * 16 + n;
        float v = (k < F_IN) ? W1[k * HID + col] : 0.f;
        Wsw[idx] = f2bf(v);
    }
    __shared__ int h[NBUCK];
    for (int j = t; j < NBUCK; j += 256) h[j] = 0;
    __syncthreads();
    int i0 = blk * CHUNK, i1 = i0 + CHUNK;
    for (int i = i0 + t * 2; i < i1; i += 512) {
        int2 sv = *(const int2*)&ei[i];
        int2 dv = *(const int2*)&ei[N_EDGES + i];
        *(float2*)&out_edges[i] = make_float2((float)sv.x, (float)sv.y);
        *(float2*)&out_edges[N_EDGES + i] = make_float2((float)dv.x, (float)dv.y);
        atomicAdd(&h[dv.x >> BSHIFT], 1);
        atomicAdd(&h[dv.y >> BSHIFT], 1);
    }
    __syncthreads();
    for (int j = t; j < NBUCK; j += 256) hist[j * NBLK + blk] = h[j];
}

// ---- GEMM1 via bf16 MFMA: h1 (fp8 e4m3) = x @ W1, fused s1/d1 (fp32) ----
#define ASTRIDE 200
__global__ __launch_bounds__(256, 4) void k_gemm1(const float* __restrict__ x,
                                                  const unsigned short* __restrict__ Wsw,
                                                  const float* __restrict__ a1s,
                                                  const float* __restrict__ a1d,
                                                  unsigned char* __restrict__ h1,
                                                  float* __restrict__ s1,
                                                  float* __restrict__ d1) {
    __shared__ unsigned short Ah[64 * ASTRIDE];
    const int tid = threadIdx.x;
    const int base = blockIdx.x * 64;
    const bool full = (base + 64 <= N_NODES);   // all but last block

    for (int i = tid; i < 64 * 35; i += 256) {
        int nl = i / 35, kk = 165 + (i - nl * 35);
        Ah[nl * ASTRIDE + kk] = 0;
    }
    const int fbase = base * F_IN;
    const int flim = N_NODES * F_IN;
    // staging: incremental (node,kk) tracking -- no per-float4 divide
    {
        int i4 = tid * 4;                 // flat float offset in tile [0, 10560)
        int nl = i4 / F_IN;
        int kk = i4 - nl * F_IN;
#pragma unroll
        for (int it = 0; it < 11; it++) {
            if (i4 < 64 * F_IN) {
                int f = fbase + i4;
                float vv[4];
                if (full || f + 4 <= flim) {
                    float4 v = *(const float4*)&x[f];
                    vv[0] = v.x; vv[1] = v.y; vv[2] = v.z; vv[3] = v.w;
                } else {
#pragma unroll
                    for (int e = 0; e < 4; e++) vv[e] = (f + e < flim) ? x[f + e] : 0.f;
                }
                int n0 = nl, k0 = kk;
#pragma unroll
                for (int e = 0; e < 4; e++) {
                    Ah[n0 * ASTRIDE + k0] = f2bf(vv[e]);
                    k0++;
                    if (k0 == F_IN) { k0 = 0; n0++; }
                }
            }
            i4 += 1024;                    // 1024 = 6*165 + 34
            nl += 6; kk += 34;
            if (kk >= F_IN) { kk -= F_IN; nl++; }
        }
    }
    __syncthreads();

    const int lane = tid & 63;
    const int w = tid >> 6;
    const int m16 = lane & 15;
    const int q = lane >> 4;
    f32x4 acc[4];
#pragma unroll
    for (int t = 0; t < 4; t++) acc[t] = (f32x4){0.f, 0.f, 0.f, 0.f};

    const unsigned short* arow = &Ah[(w * 16 + m16) * ASTRIDE];
    const short8* Wsw8 = (const short8*)Wsw;
#pragma unroll
    for (int c = 0; c < 6; c++) {
        short8 a = *(const short8*)&arow[c * 32 + q * 8];
#pragma unroll
        for (int t = 0; t < 4; t++) {
            short8 b = Wsw8[(c * 4 + q) * 64 + t * 16 + m16];
            acc[t] = __builtin_amdgcn_mfma_f32_16x16x32_bf16(a, b, acc[t], 0, 0, 0);
        }
    }

    float as_l[4], ad_l[4];
#pragma unroll
    for (int t = 0; t < 4; t++) { as_l[t] = a1s[t * 16 + m16]; ad_l[t] = a1d[t * 16 + m16]; }
#pragma unroll
    for (int r = 0; r < 4; r++) {
        int node = base + w * 16 + q * 4 + r;
        bool ok = node < N_NODES;
        float ps = 0.f, pd = 0.f;
#pragma unroll
        for (int t = 0; t < 4; t++) {
            float v = acc[t][r];
            if (ok) h1[(size_t)node * HID + t * 16 + m16] = f2fp8(v);
            ps += v * as_l[t];
            pd += v * ad_l[t];
        }
#pragma unroll
        for (int off = 1; off < 16; off <<= 1) {
            ps += __shfl_xor(ps, off);
            pd += __shfl_xor(pd, off);
        }
        if (ok && m16 == 0) { s1[node] = ps; d1[node] = pd; }
    }
}

// ---- exclusive scan (2 levels; level-3 folded into consumers) ----
__global__ void k_scan1(int* __restrict__ a, int* __restrict__ bsum) {
    __shared__ int sd[256];
    int i = blockIdx.x * 256 + threadIdx.x;
    int v = a[i];
    sd[threadIdx.x] = v;
    __syncthreads();
    for (int off = 1; off < 256; off <<= 1) {
        int t = (threadIdx.x >= off) ? sd[threadIdx.x - off] : 0;
        __syncthreads();
        sd[threadIdx.x] += t;
        __syncthreads();
    }
    a[i] = sd[threadIdx.x] - v;
    if (threadIdx.x == 255) bsum[blockIdx.x] = sd[255];
}

__global__ void k_scan2(int* __restrict__ bsum, int nb) {
    __shared__ int sd[256];
    int t = threadIdx.x;
    int v = (t < nb) ? bsum[t] : 0;
    sd[t] = v;
    __syncthreads();
    for (int off = 1; off < 256; off <<= 1) {
        int u = (t >= off) ? sd[t - off] : 0;
        __syncthreads();
        sd[t] += u;
        __syncthreads();
    }
    if (t < nb) bsum[t] = sd[t] - v;
}

// ---- pass A3: partition edges (bsum add folded in) ----
__global__ __launch_bounds__(256) void k_part(const int* __restrict__ ei,
                                              const int* __restrict__ off,
                                              const int* __restrict__ bsum,
                                              unsigned* __restrict__ pairs) {
    __shared__ int base_s[NBUCK];
    __shared__ int cnt[NBUCK];
    int blk = blockIdx.x, t = threadIdx.x;
    for (int j = t; j < NBUCK; j += 256) {
        base_s[j] = off[j * NBLK + blk] + bsum[j];
        cnt[j] = 0;
    }
    __syncthreads();
    int i0 = blk * CHUNK, i1 = i0 + CHUNK;
    for (int i = i0 + t * 2; i < i1; i += 512) {
        int2 sv = *(const int2*)&ei[i];
        int2 dv = *(const int2*)&ei[N_EDGES + i];
        int b0 = dv.x >> BSHIFT;
        int p0 = base_s[b0] + atomicAdd(&cnt[b0], 1);
        pairs[p0] = ((unsigned)sv.x << BSHIFT) | (unsigned)(dv.x & BMASK);
        int b1v = dv.y >> BSHIFT;
        int p1 = base_s[b1v] + atomicAdd(&cnt[b1v], 1);
        pairs[p1] = ((unsigned)sv.y << BSHIFT) | (unsigned)(dv.y & BMASK);
    }
}

// ---- pass B: per-bucket CSR build (bsum add folded in) ----
__global__ __launch_bounds__(512) void k_build2(const unsigned* __restrict__ pairs,
                                                const int* __restrict__ off,
                                                const int* __restrict__ bsum,
                                                int* __restrict__ row_ptr,
                                                int* __restrict__ deg,
                                                int* __restrict__ csr) {
    __shared__ int hcnt[512];
    __shared__ int cur[512];
    int b = blockIdx.x, t = threadIdx.x;
    hcnt[t] = 0;
    __syncthreads();
    int rs = off[b * NBLK] + bsum[b];
    int re = (b == NBUCK - 1) ? N_EDGES : off[(b + 1) * NBLK] + bsum[b + 1];
    for (int j = rs + t; j < re; j += 512)
        atomicAdd(&hcnt[pairs[j] & BMASK], 1);
    __syncthreads();
    int v = hcnt[t];
    cur[t] = v;
    __syncthreads();
    for (int o = 1; o < 512; o <<= 1) {
        int u = (t >= o) ? cur[t - o] : 0;
        __syncthreads();
        cur[t] += u;
        __syncthreads();
    }
    int excl = cur[t] - v;
    __syncthreads();
    cur[t] = rs + excl;
    int node = b * 512 + t;
    if (node < N_NODES) {
        row_ptr[node] = rs + excl;
        deg[node] = v;
    }
    __syncthreads();
    for (int j = rs + t; j < re; j += 512) {
        unsigned p = pairs[j];
        int pos = atomicAdd(&cur[p & BMASK], 1);
        csr[pos] = (int)(p >> BSHIFT);
    }
}

// ---- layer-1 aggregation + fused layer-2 GEMM (h1 fp8, 64B rows) ----
// 4 nodes/wave, 16 lanes/node. Batch 16: one batch covers a full deg~16
// node -- 16 gather instructions in flight per group (64/wave).
// launch_bounds(256,6): 85 VGPRs, no spill with the 48-reg batch live set.
__global__ __launch_bounds__(256, 6) void k_agg1(const unsigned char* __restrict__ h1,
                                                 const float* __restrict__ s1,
                                                 const float* __restrict__ d1,
                                                 const int* __restrict__ row_ptr,
                                                 const int* __restrict__ deg,
                                                 const int* __restrict__ csr,
                                                 const float* __restrict__ b1,
                                                 const float* __restrict__ W2,
                                                 const float* __restrict__ a2s,
                                                 const float* __restrict__ a2d,
                                                 uint2* __restrict__ node2,
                                                 float* __restrict__ d2arr) {
    int gwid = (blockIdx.x * blockDim.x + threadIdx.x) >> 6;
    int lane = threadIdx.x & 63;
    int node = gwid * 4 + (lane >> 4);
    int cg = lane & 15;
    if (node >= N_NODES) return;
    float di = d1[node];
    int rs = row_ptr[node], re = rs + deg[node];
    float dpart = 0.f;
    float4 acc = make_float4(0.f, 0.f, 0.f, 0.f);
    const unsigned char* hb = h1 + cg * 4;

    for (int j0 = rs; j0 < re; j0 += 16) {
        int sv[16]; float ev[16];
#pragma unroll
        for (int k = 0; k < 16; k++) {
            int jk = j0 + k;
            int jc = jk < re ? jk : (re - 1);
            sv[k] = csr[jc];                       // same addr across 16 lanes: broadcast
            float e = __expf(lrelu(s1[sv[k]] + di));
            ev[k] = (jk < re) ? e : 0.f;
        }
        unsigned uv[16];
#pragma unroll
        for (int k = 0; k < 16; k++)
            uv[k] = *(const unsigned*)&hb[(size_t)sv[k] << 6];   // 16 gathers in flight
#pragma unroll
        for (int k = 0; k < 16; k++) {
            f32x2 lo = __builtin_amdgcn_cvt_pk_f32_fp8((int)uv[k], false);
            f32x2 hi = __builtin_amdgcn_cvt_pk_f32_fp8((int)uv[k], true);
            dpart += ev[k];
            acc.x += ev[k] * lo.x; acc.y += ev[k] * lo.y;
            acc.z += ev[k] * hi.x; acc.w += ev[k] * hi.y;
        }
    }

    float ees = __expf(lrelu(s1[node] + di));
    unsigned us = *(const unsigned*)&hb[(size_t)node << 6];
    f32x2 slo = __builtin_amdgcn_cvt_pk_f32_fp8((int)us, false);
    f32x2 shi = __builtin_amdgcn_cvt_pk_f32_fp8((int)us, true);
    float denom = dpart + ees;
    acc.x += ees * slo.x; acc.y += ees * slo.y;
    acc.z += ees * shi.x; acc.w += ees * shi.y;
    float inv = 1.f / denom;
    float4 bb = *(const float4*)&b1[cg * 4];
    float o0 = fmaxf(acc.x * inv + bb.x, 0.f);
    float o1 = fmaxf(acc.y * inv + bb.y, 0.f);
    float o2 = fmaxf(acc.z * inv + bb.z, 0.f);
    float o3 = fmaxf(acc.w * inv + bb.w, 0.f);
    float2 w0 = *(const float2*)&W2[(cg * 4 + 0) * 2];
    float2 w1 = *(const float2*)&W2[(cg * 4 + 1) * 2];
    float2 w2 = *(const float2*)&W2[(cg * 4 + 2) * 2];
    float2 w3 = *(const float2*)&W2[(cg * 4 + 3) * 2];
    float p0 = o0 * w0.x + o1 * w1.x + o2 * w2.x + o3 * w3.x;
    float p1 = o0 * w0.y + o1 * w1.y + o2 * w2.y + o3 * w3.y;
#pragma unroll
    for (int off = 1; off < 16; off <<= 1) {
        p0 += __shfl_xor(p0, off);
        p1 += __shfl_xor(p1, off);
    }
    if (cg == 0) {
        float s2 = p0 * a2s[0] + p1 * a2s[1];
        float d2v = p0 * a2d[0] + p1 * a2d[1];
        unsigned pk = (unsigned)f2bf(p0) | ((unsigned)f2bf(p1) << 16);
        node2[node] = make_uint2(pk, __float_as_uint(s2));
        d2arr[node] = d2v;
    }
}

// ---- layer-2 aggregation: 8 nodes/wave, 8 lanes/node, batch-2 per lane ----
__global__ __launch_bounds__(256, 8) void k_agg2(const uint2* __restrict__ node2,
                                                 const float* __restrict__ d2arr,
                                                 const int* __restrict__ row_ptr,
                                                 const int* __restrict__ deg,
                                                 const int* __restrict__ csr,
                                                 const float* __restrict__ b2,
                                                 float* __restrict__ out) {
    int wid = (blockIdx.x * blockDim.x + threadIdx.x) >> 6;
    int lane = threadIdx.x & 63;
    int node = wid * 8 + (lane >> 3);
    int eg = lane & 7;
    if (node >= N_NODES) return;
    uint2 vi = node2[node];
    float d2 = d2arr[node];
    float denom = 0.f, p0 = 0.f, p1 = 0.f;
    int rs = row_ptr[node], re = rs + deg[node];
    for (int j = rs + eg; j < re; j += 16) {
        int j2 = j + 8;
        int j2c = j2 < re ? j2 : (re - 1);
        int sa = csr[j];
        int sb = csr[j2c];
        uint2 va = node2[sa];
        uint2 vb = node2[sb];
        float ea = __expf(lrelu(__uint_as_float(va.y) + d2));
        float eb = __expf(lrelu(__uint_as_float(vb.y) + d2));
        if (j2 >= re) eb = 0.f;
        denom += ea + eb;
        p0 += ea * bflo(va.x) + eb * bflo(vb.x);
        p1 += ea * bfhi(va.x) + eb * bfhi(vb.x);
    }
#pragma unroll
    for (int off = 1; off < 8; off <<= 1) {
        denom += __shfl_xor(denom, off);
        p0 += __shfl_xor(p0, off);
        p1 += __shfl_xor(p1, off);
    }
    if (eg == 0) {
        float ee = __expf(lrelu(__uint_as_float(vi.y) + d2));
        denom += ee;
        p0 += ee * bflo(vi.x);
        p1 += ee * bfhi(vi.x);
        out[(size_t)node * 2 + 0] = p0 / denom + b2[0];
        out[(size_t)node * 2 + 1] = p1 / denom + b2[1];
    }
}

extern "C" void kernel_launch(void* const* d_in, const int* in_sizes, int n_in,
                              void* d_out, int out_size, void* d_ws, size_t ws_size,
                              hipStream_t stream) {
    const float* x   = (const float*)d_in[0];
    const int*   ei  = (const int*)d_in[1];
    const float* W1  = (const float*)d_in[2];
    const float* a1s = (const float*)d_in[3];
    const float* a1d = (const float*)d_in[4];
    const float* b1  = (const float*)d_in[5];
    const float* W2  = (const float*)d_in[6];
    const float* a2s = (const float*)d_in[7];
    const float* a2d = (const float*)d_in[8];
    const float* b2  = (const float*)d_in[9];
    float* out = (float*)d_out;

    // workspace layout (~23 MB)
    unsigned char* h1 = (unsigned char*)d_ws;         // N*64 fp8 (6.4 MB)
    float* s1      = (float*)(h1 + (size_t)N_NODES * HID);
    float* d1      = s1 + N_NODES;
    float* d2arr   = d1 + N_NODES;                    // N
    uint2* node2   = (uint2*)(d2arr + N_NODES);       // N (8B each)
    int* row_ptr   = (int*)(node2 + N_NODES);         // N
    int* deg       = row_ptr + N_NODES;               // N
    int* off       = deg + N_NODES;                   // MSCAN
    int* bsum      = off + MSCAN + 64;                // 256
    int* csr       = bsum + 256;                      // E (6.4 MB)
    unsigned* pairs = (unsigned*)(csr + N_EDGES);     // E (6.4 MB)
    unsigned short* Wsw = (unsigned short*)(pairs + N_EDGES);  // 12288

    k_hist<<<NBLK, 256, 0, stream>>>(ei, off, out + 2 * N_NODES, W1, Wsw);
    k_gemm1<<<(N_NODES + 63) / 64, 256, 0, stream>>>(x, Wsw, a1s, a1d, h1, s1, d1);
    k_scan1<<<MSCAN / 256, 256, 0, stream>>>(off, bsum);
    k_scan2<<<1, 256, 0, stream>>>(bsum, MSCAN / 256);
    k_part<<<NBLK, 256, 0, stream>>>(ei, off, bsum, pairs);
    k_build2<<<NBUCK, 512, 0, stream>>>(pairs, off, bsum, row_ptr, deg, csr);
    k_agg1<<<(N_NODES + 15) / 16, 256, 0, stream>>>(h1, s1, d1, row_ptr, deg, csr,
                                                    b1, W2, a2s, a2d, node2, d2arr);
    k_agg2<<<(N_NODES + 31) / 32, 256, 0, stream>>>(node2, d2arr, row_ptr, deg, csr, b2, out);
}

// Round 13
// 209.681 us; speedup vs baseline: 1.0198x; 1.0198x over previous
//
#include <hip/hip_runtime.h>
#include <hip/hip_bf16.h>
#include <math.h>

#define N_NODES 100000
#define N_EDGES 1600000
#define F_IN 165
#define HID 64
#define SLOPE 0.2f

#define NBUCK 196          // ceil(N_NODES / 512) buckets of 512 nodes
#define BSHIFT 9           // 512 nodes per bucket
#define BMASK 511
#define NBLK 256           // partition blocks
#define CHUNK 6250         // edges per partition block (256*6250 == 1.6M)
#define MSCAN (NBUCK * NBLK)   // 50176 scan elements

typedef short short8 __attribute__((ext_vector_type(8)));
typedef float f32x4 __attribute__((ext_vector_type(4)));
typedef float f32x2 __attribute__((ext_vector_type(2)));

__device__ __forceinline__ float lrelu(float x) { return x > 0.f ? x : SLOPE * x; }

__device__ __forceinline__ unsigned short f2bf(float f) {
    unsigned u = __float_as_uint(f);
    u += 0x7FFFu + ((u >> 16) & 1u);
    return (unsigned short)(u >> 16);
}
__device__ __forceinline__ float bflo(unsigned u) { return __uint_as_float(u << 16); }
__device__ __forceinline__ float bfhi(unsigned u) { return __uint_as_float(u & 0xFFFF0000u); }
__device__ __forceinline__ unsigned char f2fp8(float f) {
    return (unsigned char)(__builtin_amdgcn_cvt_pk_fp8_f32(f, f, 0, false) & 0xFF);
}

// ---- pass A1: bucket histogram + edge cast + (fused) W1 swizzle ----
__global__ __launch_bounds__(256) void k_hist(const int* __restrict__ ei,
                                              int* __restrict__ hist,
                                              float* __restrict__ out_edges,
                                              const float* __restrict__ W1,
                                              unsigned short* __restrict__ Wsw) {
    int blk = blockIdx.x, t = threadIdx.x;
    int idx = blk * 256 + t;
    if (idx < 12288) {
        int j = idx & 7;
        int r = idx >> 3;
        int n = r & 15; r >>= 4;
        int tt = r & 3; r >>= 2;
        int q = r & 3;  int c = r >> 2;
        int k = c * 32 + q * 8 + j;
        int col = tt * 16 + n;
        float v = (k < F_IN) ? W1[k * HID + col] : 0.f;
        Wsw[idx] = f2bf(v);
    }
    __shared__ int h[NBUCK];
    for (int j = t; j < NBUCK; j += 256) h[j] = 0;
    __syncthreads();
    int i0 = blk * CHUNK, i1 = i0 + CHUNK;
    for (int i = i0 + t * 2; i < i1; i += 512) {
        int2 sv = *(const int2*)&ei[i];
        int2 dv = *(const int2*)&ei[N_EDGES + i];
        *(float2*)&out_edges[i] = make_float2((float)sv.x, (float)sv.y);
        *(float2*)&out_edges[N_EDGES + i] = make_float2((float)dv.x, (float)dv.y);
        atomicAdd(&h[dv.x >> BSHIFT], 1);
        atomicAdd(&h[dv.y >> BSHIFT], 1);
    }
    __syncthreads();
    for (int j = t; j < NBUCK; j += 256) hist[j * NBLK + blk] = h[j];
}

// ---- GEMM1 via bf16 MFMA: h1 (fp8 e4m3) = x @ W1, fused s1/d1 (fp32) ----
#define ASTRIDE 200
__global__ __launch_bounds__(256, 4) void k_gemm1(const float* __restrict__ x,
                                                  const unsigned short* __restrict__ Wsw,
                                                  const float* __restrict__ a1s,
                                                  const float* __restrict__ a1d,
                                                  unsigned char* __restrict__ h1,
                                                  float* __restrict__ s1,
                                                  float* __restrict__ d1) {
    __shared__ unsigned short Ah[64 * ASTRIDE];
    const int tid = threadIdx.x;
    const int base = blockIdx.x * 64;
    const bool full = (base + 64 <= N_NODES);   // all but last block

    for (int i = tid; i < 64 * 35; i += 256) {
        int nl = i / 35, kk = 165 + (i - nl * 35);
        Ah[nl * ASTRIDE + kk] = 0;
    }
    const int fbase = base * F_IN;
    const int flim = N_NODES * F_IN;
    // staging: incremental (node,kk) tracking -- no per-float4 divide
    {
        int i4 = tid * 4;                 // flat float offset in tile [0, 10560)
        int nl = i4 / F_IN;
        int kk = i4 - nl * F_IN;
#pragma unroll
        for (int it = 0; it < 11; it++) {
            if (i4 < 64 * F_IN) {
                int f = fbase + i4;
                float vv[4];
                if (full || f + 4 <= flim) {
                    float4 v = *(const float4*)&x[f];
                    vv[0] = v.x; vv[1] = v.y; vv[2] = v.z; vv[3] = v.w;
                } else {
#pragma unroll
                    for (int e = 0; e < 4; e++) vv[e] = (f + e < flim) ? x[f + e] : 0.f;
                }
                int n0 = nl, k0 = kk;
#pragma unroll
                for (int e = 0; e < 4; e++) {
                    Ah[n0 * ASTRIDE + k0] = f2bf(vv[e]);
                    k0++;
                    if (k0 == F_IN) { k0 = 0; n0++; }
                }
            }
            i4 += 1024;                    // 1024 = 6*165 + 34
            nl += 6; kk += 34;
            if (kk >= F_IN) { kk -= F_IN; nl++; }
        }
    }
    __syncthreads();

    const int lane = tid & 63;
    const int w = tid >> 6;
    const int m16 = lane & 15;
    const int q = lane >> 4;
    f32x4 acc[4];
#pragma unroll
    for (int t = 0; t < 4; t++) acc[t] = (f32x4){0.f, 0.f, 0.f, 0.f};

    const unsigned short* arow = &Ah[(w * 16 + m16) * ASTRIDE];
    const short8* Wsw8 = (const short8*)Wsw;
#pragma unroll
    for (int c = 0; c < 6; c++) {
        short8 a = *(const short8*)&arow[c * 32 + q * 8];
#pragma unroll
        for (int t = 0; t < 4; t++) {
            short8 b = Wsw8[(c * 4 + q) * 64 + t * 16 + m16];
            acc[t] = __builtin_amdgcn_mfma_f32_16x16x32_bf16(a, b, acc[t], 0, 0, 0);
        }
    }

    float as_l[4], ad_l[4];
#pragma unroll
    for (int t = 0; t < 4; t++) { as_l[t] = a1s[t * 16 + m16]; ad_l[t] = a1d[t * 16 + m16]; }
#pragma unroll
    for (int r = 0; r < 4; r++) {
        int node = base + w * 16 + q * 4 + r;
        bool ok = node < N_NODES;
        float ps = 0.f, pd = 0.f;
#pragma unroll
        for (int t = 0; t < 4; t++) {
            float v = acc[t][r];
            if (ok) h1[(size_t)node * HID + t * 16 + m16] = f2fp8(v);
            ps += v * as_l[t];
            pd += v * ad_l[t];
        }
#pragma unroll
        for (int off = 1; off < 16; off <<= 1) {
            ps += __shfl_xor(ps, off);
            pd += __shfl_xor(pd, off);
        }
        if (ok && m16 == 0) { s1[node] = ps; d1[node] = pd; }
    }
}

// ---- exclusive scan (2 levels; level-3 folded into consumers) ----
__global__ void k_scan1(int* __restrict__ a, int* __restrict__ bsum) {
    __shared__ int sd[256];
    int i = blockIdx.x * 256 + threadIdx.x;
    int v = a[i];
    sd[threadIdx.x] = v;
    __syncthreads();
    for (int off = 1; off < 256; off <<= 1) {
        int t = (threadIdx.x >= off) ? sd[threadIdx.x - off] : 0;
        __syncthreads();
        sd[threadIdx.x] += t;
        __syncthreads();
    }
    a[i] = sd[threadIdx.x] - v;
    if (threadIdx.x == 255) bsum[blockIdx.x] = sd[255];
}

__global__ void k_scan2(int* __restrict__ bsum, int nb) {
    __shared__ int sd[256];
    int t = threadIdx.x;
    int v = (t < nb) ? bsum[t] : 0;
    sd[t] = v;
    __syncthreads();
    for (int off = 1; off < 256; off <<= 1) {
        int u = (t >= off) ? sd[t - off] : 0;
        __syncthreads();
        sd[t] += u;
        __syncthreads();
    }
    if (t < nb) bsum[t] = sd[t] - v;
}

// ---- pass A3: partition edges (bsum add folded in) ----
__global__ __launch_bounds__(256) void k_part(const int* __restrict__ ei,
                                              const int* __restrict__ off,
                                              const int* __restrict__ bsum,
                                              unsigned* __restrict__ pairs) {
    __shared__ int base_s[NBUCK];
    __shared__ int cnt[NBUCK];
    int blk = blockIdx.x, t = threadIdx.x;
    for (int j = t; j < NBUCK; j += 256) {
        base_s[j] = off[j * NBLK + blk] + bsum[j];
        cnt[j] = 0;
    }
    __syncthreads();
    int i0 = blk * CHUNK, i1 = i0 + CHUNK;
    for (int i = i0 + t * 2; i < i1; i += 512) {
        int2 sv = *(const int2*)&ei[i];
        int2 dv = *(const int2*)&ei[N_EDGES + i];
        int b0 = dv.x >> BSHIFT;
        int p0 = base_s[b0] + atomicAdd(&cnt[b0], 1);
        pairs[p0] = ((unsigned)sv.x << BSHIFT) | (unsigned)(dv.x & BMASK);
        int b1v = dv.y >> BSHIFT;
        int p1 = base_s[b1v] + atomicAdd(&cnt[b1v], 1);
        pairs[p1] = ((unsigned)sv.y << BSHIFT) | (unsigned)(dv.y & BMASK);
    }
}

// ---- pass B: per-bucket CSR build (bsum add folded in) ----
__global__ __launch_bounds__(512) void k_build2(const unsigned* __restrict__ pairs,
                                                const int* __restrict__ off,
                                                const int* __restrict__ bsum,
                                                int* __restrict__ row_ptr,
                                                int* __restrict__ deg,
                                                int* __restrict__ csr) {
    __shared__ int hcnt[512];
    __shared__ int cur[512];
    int b = blockIdx.x, t = threadIdx.x;
    hcnt[t] = 0;
    __syncthreads();
    int rs = off[b * NBLK] + bsum[b];
    int re = (b == NBUCK - 1) ? N_EDGES : off[(b + 1) * NBLK] + bsum[b + 1];
    for (int j = rs + t; j < re; j += 512)
        atomicAdd(&hcnt[pairs[j] & BMASK], 1);
    __syncthreads();
    int v = hcnt[t];
    cur[t] = v;
    __syncthreads();
    for (int o = 1; o < 512; o <<= 1) {
        int u = (t >= o) ? cur[t - o] : 0;
        __syncthreads();
        cur[t] += u;
        __syncthreads();
    }
    int excl = cur[t] - v;
    __syncthreads();
    cur[t] = rs + excl;
    int node = b * 512 + t;
    if (node < N_NODES) {
        row_ptr[node] = rs + excl;
        deg[node] = v;
    }
    __syncthreads();
    for (int j = rs + t; j < re; j += 512) {
        unsigned p = pairs[j];
        int pos = atomicAdd(&cur[p & BMASK], 1);
        csr[pos] = (int)(p >> BSHIFT);
    }
}

// ---- layer-1 aggregation + fused layer-2 GEMM (h1 fp8, 64B rows) ----
// R11-proven config: 4 nodes/wave, 16 lanes/node, batch 8 (~24 live regs,
// no spill -- batch 16 spilled to scratch, R12). 32 gathers in flight/wave.
__global__ __launch_bounds__(256, 8) void k_agg1(const unsigned char* __restrict__ h1,
                                                 const float* __restrict__ s1,
                                                 const float* __restrict__ d1,
                                                 const int* __restrict__ row_ptr,
                                                 const int* __restrict__ deg,
                                                 const int* __restrict__ csr,
                                                 const float* __restrict__ b1,
                                                 const float* __restrict__ W2,
                                                 const float* __restrict__ a2s,
                                                 const float* __restrict__ a2d,
                                                 uint2* __restrict__ node2,
                                                 float* __restrict__ d2arr) {
    int gwid = (blockIdx.x * blockDim.x + threadIdx.x) >> 6;
    int lane = threadIdx.x & 63;
    int node = gwid * 4 + (lane >> 4);
    int cg = lane & 15;
    if (node >= N_NODES) return;
    float di = d1[node];
    int rs = row_ptr[node], re = rs + deg[node];
    float dpart = 0.f;
    float4 acc = make_float4(0.f, 0.f, 0.f, 0.f);
    const unsigned char* hb = h1 + cg * 4;

    for (int j0 = rs; j0 < re; j0 += 8) {
        int sv[8]; float ev[8];
#pragma unroll
        for (int k = 0; k < 8; k++) {
            int jk = j0 + k;
            int jc = jk < re ? jk : (re - 1);
            sv[k] = csr[jc];                       // same addr across 16 lanes: broadcast
            float e = __expf(lrelu(s1[sv[k]] + di));
            ev[k] = (jk < re) ? e : 0.f;
        }
        unsigned uv[8];
#pragma unroll
        for (int k = 0; k < 8; k++)
            uv[k] = *(const unsigned*)&hb[(size_t)sv[k] << 6];   // 8 gathers in flight
#pragma unroll
        for (int k = 0; k < 8; k++) {
            f32x2 lo = __builtin_amdgcn_cvt_pk_f32_fp8((int)uv[k], false);
            f32x2 hi = __builtin_amdgcn_cvt_pk_f32_fp8((int)uv[k], true);
            dpart += ev[k];
            acc.x += ev[k] * lo.x; acc.y += ev[k] * lo.y;
            acc.z += ev[k] * hi.x; acc.w += ev[k] * hi.y;
        }
    }

    // self loop (per-lane; dpart identical across the 16 lanes of the group)
    float ees = __expf(lrelu(s1[node] + di));
    unsigned us = *(const unsigned*)&hb[(size_t)node << 6];
    f32x2 slo = __builtin_amdgcn_cvt_pk_f32_fp8((int)us, false);
    f32x2 shi = __builtin_amdgcn_cvt_pk_f32_fp8((int)us, true);
    float denom = dpart + ees;
    acc.x += ees * slo.x; acc.y += ees * slo.y;
    acc.z += ees * shi.x; acc.w += ees * shi.y;
    float inv = 1.f / denom;
    float4 bb = *(const float4*)&b1[cg * 4];
    float o0 = fmaxf(acc.x * inv + bb.x, 0.f);
    float o1 = fmaxf(acc.y * inv + bb.y, 0.f);
    float o2 = fmaxf(acc.z * inv + bb.z, 0.f);
    float o3 = fmaxf(acc.w * inv + bb.w, 0.f);
    float2 w0 = *(const float2*)&W2[(cg * 4 + 0) * 2];
    float2 w1 = *(const float2*)&W2[(cg * 4 + 1) * 2];
    float2 w2 = *(const float2*)&W2[(cg * 4 + 2) * 2];
    float2 w3 = *(const float2*)&W2[(cg * 4 + 3) * 2];
    float p0 = o0 * w0.x + o1 * w1.x + o2 * w2.x + o3 * w3.x;
    float p1 = o0 * w0.y + o1 * w1.y + o2 * w2.y + o3 * w3.y;
#pragma unroll
    for (int off = 1; off < 16; off <<= 1) {   // reduce within the 16-lane group
        p0 += __shfl_xor(p0, off);
        p1 += __shfl_xor(p1, off);
    }
    if (cg == 0) {
        float s2 = p0 * a2s[0] + p1 * a2s[1];
        float d2v = p0 * a2d[0] + p1 * a2d[1];
        unsigned pk = (unsigned)f2bf(p0) | ((unsigned)f2bf(p1) << 16);
        node2[node] = make_uint2(pk, __float_as_uint(s2));
        d2arr[node] = d2v;
    }
}

// ---- layer-2 aggregation: 8 nodes/wave, 8 lanes/node, batch-2 per lane ----
__global__ __launch_bounds__(256, 8) void k_agg2(const uint2* __restrict__ node2,
                                                 const float* __restrict__ d2arr,
                                                 const int* __restrict__ row_ptr,
                                                 const int* __restrict__ deg,
                                                 const int* __restrict__ csr,
                                                 const float* __restrict__ b2,
                                                 float* __restrict__ out) {
    int wid = (blockIdx.x * blockDim.x + threadIdx.x) >> 6;
    int lane = threadIdx.x & 63;
    int node = wid * 8 + (lane >> 3);
    int eg = lane & 7;
    if (node >= N_NODES) return;
    uint2 vi = node2[node];
    float d2 = d2arr[node];
    float denom = 0.f, p0 = 0.f, p1 = 0.f;
    int rs = row_ptr[node], re = rs + deg[node];
    for (int j = rs + eg; j < re; j += 16) {
        int j2 = j + 8;
        int j2c = j2 < re ? j2 : (re - 1);
        int sa = csr[j];
        int sb = csr[j2c];
        uint2 va = node2[sa];
        uint2 vb = node2[sb];
        float ea = __expf(lrelu(__uint_as_float(va.y) + d2));
        float eb = __expf(lrelu(__uint_as_float(vb.y) + d2));
        if (j2 >= re) eb = 0.f;
        denom += ea + eb;
        p0 += ea * bflo(va.x) + eb * bflo(vb.x);
        p1 += ea * bfhi(va.x) + eb * bfhi(vb.x);
    }
#pragma unroll
    for (int off = 1; off < 8; off <<= 1) {
        denom += __shfl_xor(denom, off);
        p0 += __shfl_xor(p0, off);
        p1 += __shfl_xor(p1, off);
    }
    if (eg == 0) {
        float ee = __expf(lrelu(__uint_as_float(vi.y) + d2));
        denom += ee;
        p0 += ee * bflo(vi.x);
        p1 += ee * bfhi(vi.x);
        out[(size_t)node * 2 + 0] = p0 / denom + b2[0];
        out[(size_t)node * 2 + 1] = p1 / denom + b2[1];
    }
}

extern "C" void kernel_launch(void* const* d_in, const int* in_sizes, int n_in,
                              void* d_out, int out_size, void* d_ws, size_t ws_size,
                              hipStream_t stream) {
    const float* x   = (const float*)d_in[0];
    const int*   ei  = (const int*)d_in[1];
    const float* W1  = (const float*)d_in[2];
    const float* a1s = (const float*)d_in[3];
    const float* a1d = (const float*)d_in[4];
    const float* b1  = (const float*)d_in[5];
    const float* W2  = (const float*)d_in[6];
    const float* a2s = (const float*)d_in[7];
    const float* a2d = (const float*)d_in[8];
    const float* b2  = (const float*)d_in[9];
    float* out = (float*)d_out;

    // workspace layout (~23 MB)
    unsigned char* h1 = (unsigned char*)d_ws;         // N*64 fp8 (6.4 MB)
    float* s1      = (float*)(h1 + (size_t)N_NODES * HID);
    float* d1      = s1 + N_NODES;
    float* d2arr   = d1 + N_NODES;                    // N
    uint2* node2   = (uint2*)(d2arr + N_NODES);       // N (8B each)
    int* row_ptr   = (int*)(node2 + N_NODES);         // N
    int* deg       = row_ptr + N_NODES;               // N
    int* off       = deg + N_NODES;                   // MSCAN
    int* bsum      = off + MSCAN + 64;                // 256
    int* csr       = bsum + 256;                      // E (6.4 MB)
    unsigned* pairs = (unsigned*)(csr + N_EDGES);     // E (6.4 MB)
    unsigned short* Wsw = (unsigned short*)(pairs + N_EDGES);  // 12288

    k_hist<<<NBLK, 256, 0, stream>>>(ei, off, out + 2 * N_NODES, W1, Wsw);
    k_gemm1<<<(N_NODES + 63) / 64, 256, 0, stream>>>(x, Wsw, a1s, a1d, h1, s1, d1);
    k_scan1<<<MSCAN / 256, 256, 0, stream>>>(off, bsum);
    k_scan2<<<1, 256, 0, stream>>>(bsum, MSCAN / 256);
    k_part<<<NBLK, 256, 0, stream>>>(ei, off, bsum, pairs);
    k_build2<<<NBUCK, 512, 0, stream>>>(pairs, off, bsum, row_ptr, deg, csr);
    k_agg1<<<(N_NODES + 15) / 16, 256, 0, stream>>>(h1, s1, d1, row_ptr, deg, csr,
                                                    b1, W2, a2s, a2d, node2, d2arr);
    k_agg2<<<(N_NODES + 31) / 32, 256, 0, stream>>>(node2, d2arr, row_ptr, deg, csr, b2, out);
}